// Round 1
// baseline (589.021 us; speedup 1.0000x reference)
//
#include <hip/hip_runtime.h>
#include <hip/hip_bf16.h>

// TAMCaD_T fused attention-over-variables.
// q,k,v: (B=16, G=32, H=32, S=4096) fp32, s contiguous.
// Per (b,s): logits[g][f] = scale * sum_d q[g,d]k[f,d]; attn = softmax_f; x[g,d] = sum_f attn*v[f,d].
// Outputs (concat fp32): x (B,G*H,S) | attentions (B,G,G,S) | logits (B,G,G,S).
// Memory-bound: 1.6 GB minimum traffic. Fused one-pass, block = (b, 8-timestep tile).

constexpr int S_LEN = 4096;
constexpr int GG = 32;   // groups (q and kv)
constexpr int HH = 32;   // hidden dim per head (dk), n_heads = 1
constexpr int TS = 8;    // timesteps per block
constexpr float SCALE = 0.17677669529663687f;  // 32^-0.5

__device__ __forceinline__ unsigned bf16pack(float a, float b) {
    // round-to-nearest-even bf16 pair packed in a u32 (lo = a, hi = b)
    unsigned ua = __float_as_uint(a);
    unsigned ub = __float_as_uint(b);
    ua = (ua + 0x7fffu + ((ua >> 16) & 1u)) >> 16;
    ub = (ub + 0x7fffu + ((ub >> 16) & 1u)) >> 16;
    return ua | (ub << 16);
}

__global__ __launch_bounds__(256, 4) void tamcad_fused(
    const float* __restrict__ q, const float* __restrict__ k,
    const float* __restrict__ v, float* __restrict__ x_out,
    float* __restrict__ attn_out, float* __restrict__ logit_out)
{
    // bf16 tiles [32 rows][32 cols][8 s] as u32 pairs; k_lds reused as attn buffer in PV.
    __shared__ unsigned k_lds[GG * HH * TS / 2];  // 4096 u32 = 16 KB
    __shared__ unsigned v_lds[GG * HH * TS / 2];  // 16 KB

    // XCD-bijective swizzle: consecutive logical s-tiles land on the same XCD (L2 line merge,
    // since each block only touches 32 B of every 64 B line). nwg = B*512, divisible by 8.
    const int nwg = gridDim.x;
    const int cpx = nwg >> 3;
    const int raw = blockIdx.x;
    const int logical = (raw & 7) * cpx + (raw >> 3);
    const int b  = logical >> 9;       // / (S/TS) = / 512
    const int st = logical & 511;
    const int s0 = st * TS;

    const int tid = threadIdx.x;
    const int gt = tid >> 5;           // 0..7  g-tile
    const int ft = (tid >> 2) & 7;     // 0..7  f-tile (QK) / d-tile (PV)
    const int sp = tid & 3;            // 0..3  s-pair (2 timesteps each)

    const int baseB = b * (GG * HH);   // row base (rows of length S)
    const float* qb = q + (size_t)baseB * S_LEN + s0;
    const float* kb = k + (size_t)baseB * S_LEN + s0;
    const float* vb = v + (size_t)baseB * S_LEN + s0;

    // ---------------- stage k, v -> LDS bf16 (swizzled) ----------------
    for (int r = tid; r < GG * HH; r += 256) {
        const int f = r >> 5, d = r & 31;
        const float4* ks = reinterpret_cast<const float4*>(kb + (size_t)r * S_LEN);
        const float4* vs = reinterpret_cast<const float4*>(vb + (size_t)r * S_LEN);
        float4 k0 = ks[0], k1 = ks[1];
        float4 v0 = vs[0], v1 = vs[1];
        uint4 pk, pv;
        pk.x = bf16pack(k0.x, k0.y); pk.y = bf16pack(k0.z, k0.w);
        pk.z = bf16pack(k1.x, k1.y); pk.w = bf16pack(k1.z, k1.w);
        pv.x = bf16pack(v0.x, v0.y); pv.y = bf16pack(v0.z, v0.w);
        pv.z = bf16pack(v1.x, v1.y); pv.w = bf16pack(v1.z, v1.w);
        // k: rotate d by f>>2 -> QK read lanes (ft) hit distinct banks
        const int dk_ = (d + (f >> 2)) & 31;
        *reinterpret_cast<uint4*>(&k_lds[(f * 32 + dk_) * 4]) = pk;
        // v: bit-rotate d -> PV read lanes (dt) hit distinct banks
        const int dv_ = ((d & 3) << 3) | (d >> 2);
        *reinterpret_cast<uint4*>(&v_lds[(f * 32 + dv_) * 4]) = pv;
    }
    __syncthreads();

    // ---------------- QK^T: acc[4g][4f][2s] ----------------
    float acc[4][4][2];
    #pragma unroll
    for (int j = 0; j < 4; ++j)
        #pragma unroll
        for (int i = 0; i < 4; ++i) { acc[j][i][0] = 0.f; acc[j][i][1] = 0.f; }

    const float* qrow[4];
    #pragma unroll
    for (int j = 0; j < 4; ++j)
        qrow[j] = qb + (size_t)((gt * 4 + j) * HH) * S_LEN + sp * 2;

    #pragma unroll 4
    for (int d = 0; d < HH; ++d) {
        float2 qv[4];
        #pragma unroll
        for (int j = 0; j < 4; ++j)
            qv[j] = *reinterpret_cast<const float2*>(qrow[j] + (size_t)d * S_LEN);
        #pragma unroll
        for (int i = 0; i < 4; ++i) {
            const int f = ft * 4 + i;
            const unsigned w = k_lds[(f * 32 + ((d + ft) & 31)) * 4 + sp];  // f>>2 == ft
            const float klo = __uint_as_float(w << 16);
            const float khi = __uint_as_float(w & 0xffff0000u);
            #pragma unroll
            for (int j = 0; j < 4; ++j) {
                acc[j][i][0] = fmaf(qv[j].x, klo, acc[j][i][0]);
                acc[j][i][1] = fmaf(qv[j].y, khi, acc[j][i][1]);
            }
        }
    }
    #pragma unroll
    for (int j = 0; j < 4; ++j)
        #pragma unroll
        for (int i = 0; i < 4; ++i) { acc[j][i][0] *= SCALE; acc[j][i][1] *= SCALE; }

    __syncthreads();   // all k_lds reads done; k_lds becomes the attn buffer

    // ---------------- softmax over f (4 local f x 8 ft lanes) ----------------
    float mx[4][2];
    #pragma unroll
    for (int j = 0; j < 4; ++j) {
        #pragma unroll
        for (int e = 0; e < 2; ++e) {
            float m = fmaxf(fmaxf(acc[j][0][e], acc[j][1][e]),
                            fmaxf(acc[j][2][e], acc[j][3][e]));
            m = fmaxf(m, __shfl_xor(m, 4));
            m = fmaxf(m, __shfl_xor(m, 8));
            m = fmaxf(m, __shfl_xor(m, 16));
            mx[j][e] = m;
        }
    }
    // store logits, then overwrite acc in place with exp(acc - m) (register pressure)
    #pragma unroll
    for (int j = 0; j < 4; ++j) {
        const int g = gt * 4 + j;
        #pragma unroll
        for (int i = 0; i < 4; ++i) {
            const int f = ft * 4 + i;
            const size_t o = (size_t)(baseB + g * GG + f) * S_LEN + s0 + sp * 2;
            *reinterpret_cast<float2*>(logit_out + o) = make_float2(acc[j][i][0], acc[j][i][1]);
            acc[j][i][0] = __expf(acc[j][i][0] - mx[j][0]);
            acc[j][i][1] = __expf(acc[j][i][1] - mx[j][1]);
        }
    }
    float inv[4][2];
    #pragma unroll
    for (int j = 0; j < 4; ++j) {
        #pragma unroll
        for (int e = 0; e < 2; ++e) {
            float s = acc[j][0][e] + acc[j][1][e] + acc[j][2][e] + acc[j][3][e];
            s += __shfl_xor(s, 4);
            s += __shfl_xor(s, 8);
            s += __shfl_xor(s, 16);
            inv[j][e] = __builtin_amdgcn_rcpf(s);
        }
    }
    // attn: store to global + pack bf16 into k_lds (linear [g][f][8s]; dt-lane reads broadcast)
    #pragma unroll
    for (int j = 0; j < 4; ++j) {
        const int g = gt * 4 + j;
        #pragma unroll
        for (int i = 0; i < 4; ++i) {
            const int f = ft * 4 + i;
            const float a0 = acc[j][i][0] * inv[j][0];
            const float a1 = acc[j][i][1] * inv[j][1];
            const size_t o = (size_t)(baseB + g * GG + f) * S_LEN + s0 + sp * 2;
            *reinterpret_cast<float2*>(attn_out + o) = make_float2(a0, a1);
            k_lds[(g * 32 + f) * 4 + sp] = bf16pack(a0, a1);
        }
    }
    __syncthreads();

    // ---------------- PV: xacc[4g][4d][2s] ----------------
    float xacc[4][4][2];
    #pragma unroll
    for (int j = 0; j < 4; ++j)
        #pragma unroll
        for (int i = 0; i < 4; ++i) { xacc[j][i][0] = 0.f; xacc[j][i][1] = 0.f; }

    const int dt = ft;
    #pragma unroll 4
    for (int f = 0; f < GG; ++f) {
        float alo[4], ahi[4];
        #pragma unroll
        for (int j = 0; j < 4; ++j) {
            const unsigned w = k_lds[((gt * 4 + j) * 32 + f) * 4 + sp];
            alo[j] = __uint_as_float(w << 16);
            ahi[j] = __uint_as_float(w & 0xffff0000u);
        }
        #pragma unroll
        for (int i = 0; i < 4; ++i) {
            // d = dt*4+i stored at pi(d) = ((d&3)<<3)|(d>>2) = i*8 + dt
            const unsigned w = v_lds[(f * 32 + i * 8 + dt) * 4 + sp];
            const float vlo = __uint_as_float(w << 16);
            const float vhi = __uint_as_float(w & 0xffff0000u);
            #pragma unroll
            for (int j = 0; j < 4; ++j) {
                xacc[j][i][0] = fmaf(alo[j], vlo, xacc[j][i][0]);
                xacc[j][i][1] = fmaf(ahi[j], vhi, xacc[j][i][1]);
            }
        }
    }
    // store x: x[b, g*32+d, s]
    #pragma unroll
    for (int j = 0; j < 4; ++j) {
        const int g = gt * 4 + j;
        #pragma unroll
        for (int i = 0; i < 4; ++i) {
            const int d = dt * 4 + i;
            const size_t o = (size_t)(baseB + g * HH + d) * S_LEN + s0 + sp * 2;
            *reinterpret_cast<float2*>(x_out + o) = make_float2(xacc[j][i][0], xacc[j][i][1]);
        }
    }
}

extern "C" void kernel_launch(void* const* d_in, const int* in_sizes, int n_in,
                              void* d_out, int out_size, void* d_ws, size_t ws_size,
                              hipStream_t stream) {
    const float* q = (const float*)d_in[0];
    const float* k = (const float*)d_in[1];
    const float* v = (const float*)d_in[2];
    float* out = (float*)d_out;
    const int n = in_sizes[0];                  // B*G*H*S = 67108864
    const int B = n / (GG * HH * S_LEN);        // 16
    float* x_out     = out;
    float* attn_out  = out + (size_t)n;
    float* logit_out = out + (size_t)2 * n;
    const int nwg = B * (S_LEN / TS);           // 8192
    tamcad_fused<<<dim3(nwg), dim3(256), 0, stream>>>(q, k, v, x_out, attn_out, logit_out);
}

// Round 2
// 513.257 us; speedup vs baseline: 1.1476x; 1.1476x over previous
//
#include <hip/hip_runtime.h>
#include <hip/hip_bf16.h>

// TAMCaD_T fused attention-over-variables.
// q,k,v: (B=16, G=32, H=32, S=4096) fp32, s contiguous.
// Per (b,s): logits[g][f] = scale * sum_d q[g,d]k[f,d]; attn = softmax_f; x[g,d] = sum_f attn*v[f,d].
// Outputs (concat fp32): x (B,G*H,S) | attentions (B,G,G,S) | logits (B,G,G,S).
// Memory-bound: 1.536 GB minimum traffic (244 us @ 6.3 TB/s).
// TS=16 so every global read/write row-segment is a full 64-B line (round 1 showed
// 1.51x write amplification at TS=8 from half-line writes).

constexpr int S_LEN = 4096;
constexpr int GG = 32;   // groups (q and kv)
constexpr int HH = 32;   // hidden dim (dk), n_heads = 1
constexpr int TS = 16;   // timesteps per block -> 64 B per row segment
constexpr float SCALE = 0.17677669529663687f;  // 32^-0.5

__device__ __forceinline__ unsigned bf16pack(float a, float b) {
    // round-to-nearest-even bf16 pair in a u32 (lo = a, hi = b)
    unsigned ua = __float_as_uint(a);
    unsigned ub = __float_as_uint(b);
    ua = (ua + 0x7fffu + ((ua >> 16) & 1u)) >> 16;
    ub = (ub + 0x7fffu + ((ub >> 16) & 1u)) >> 16;
    return ua | (ub << 16);
}

__global__ __launch_bounds__(512, 4) void tamcad_fused(
    const float* __restrict__ q, const float* __restrict__ k,
    const float* __restrict__ v, float* __restrict__ x_out,
    float* __restrict__ attn_out, float* __restrict__ logit_out)
{
    // bf16 tiles, u32-paired. Element (row, sp) lives at row*8 + (sp ^ (row&4)):
    // the XOR spreads consecutive 32-B rows across all 32 banks (staging b128
    // writes go 4-group/16-way -> 8-group/8-way = optimal) and makes QK/PV b32
    // reads conflict-free. k_lds is reused as the attn buffer for PV.
    __shared__ __align__(16) unsigned k_lds[GG * HH * TS / 2];  // 8192 u32 = 32 KB
    __shared__ __align__(16) unsigned v_lds[GG * HH * TS / 2];  // 32 KB

    // XCD-bijective swizzle: consecutive logical s-tiles -> same XCD (L2 locality).
    // nwg = 4096, divisible by 8.
    const int nwg = gridDim.x;
    const int cpx = nwg >> 3;
    const int raw = blockIdx.x;
    const int logical = (raw & 7) * cpx + (raw >> 3);
    const int b  = logical >> 8;       // / (S/TS = 256)
    const int st = logical & 255;
    const int s0 = st * TS;

    const int tid = threadIdx.x;
    const int gt = tid >> 6;           // 0..7  g-tile (one per wave)
    const int ft = (tid >> 3) & 7;     // 0..7  f-tile (QK) / d-tile (PV)
    const int sp = tid & 7;            // 0..7  s-pair (2 timesteps each)

    const int baseB = b * (GG * HH);   // row base (rows of length S)
    const float* qb = q + (size_t)baseB * S_LEN + s0;
    const float* kb = k + (size_t)baseB * S_LEN + s0;
    const float* vb = v + (size_t)baseB * S_LEN + s0;

    // ---------------- stage k, v -> LDS bf16 (swizzled) ----------------
    for (int r = tid; r < GG * HH; r += 512) {
        const int f = r >> 5, d = r & 31;
        const float4* ks = reinterpret_cast<const float4*>(kb + (size_t)r * S_LEN);
        const float4* vs = reinterpret_cast<const float4*>(vb + (size_t)r * S_LEN);
        float4 k0 = ks[0], k1 = ks[1], k2 = ks[2], k3 = ks[3];
        float4 v0 = vs[0], v1 = vs[1], v2 = vs[2], v3 = vs[3];
        uint4 kl, kh, vl, vh;
        kl.x = bf16pack(k0.x, k0.y); kl.y = bf16pack(k0.z, k0.w);
        kl.z = bf16pack(k1.x, k1.y); kl.w = bf16pack(k1.z, k1.w);
        kh.x = bf16pack(k2.x, k2.y); kh.y = bf16pack(k2.z, k2.w);
        kh.z = bf16pack(k3.x, k3.y); kh.w = bf16pack(k3.z, k3.w);
        vl.x = bf16pack(v0.x, v0.y); vl.y = bf16pack(v0.z, v0.w);
        vl.z = bf16pack(v1.x, v1.y); vl.w = bf16pack(v1.z, v1.w);
        vh.x = bf16pack(v2.x, v2.y); vh.y = bf16pack(v2.z, v2.w);
        vh.z = bf16pack(v3.x, v3.y); vh.w = bf16pack(v3.z, v3.w);
        // k: rotate d by f>>2 -> QK ft-lane reads hit distinct banks
        const int rk = f * 32 + ((d + (f >> 2)) & 31);
        const int xk = rk & 4;   // bank-spread XOR (swap 16-B halves on odd quads)
        *reinterpret_cast<uint4*>(&k_lds[rk * 8 + xk])       = kl;  // sp 0-3
        *reinterpret_cast<uint4*>(&k_lds[rk * 8 + (4 ^ xk)]) = kh;  // sp 4-7
        // v: bit-rotate d -> PV dt-lane reads hit distinct banks
        const int rv = f * 32 + (((d & 3) << 3) | (d >> 2));
        const int xv = rv & 4;
        *reinterpret_cast<uint4*>(&v_lds[rv * 8 + xv])       = vl;
        *reinterpret_cast<uint4*>(&v_lds[rv * 8 + (4 ^ xv)]) = vh;
    }
    __syncthreads();

    // ---------------- QK^T: acc[4g][4f][2s] ----------------
    float acc[4][4][2];
    #pragma unroll
    for (int j = 0; j < 4; ++j)
        #pragma unroll
        for (int i = 0; i < 4; ++i) { acc[j][i][0] = 0.f; acc[j][i][1] = 0.f; }

    const float* qrow[4];
    #pragma unroll
    for (int j = 0; j < 4; ++j)
        qrow[j] = qb + (size_t)((gt * 4 + j) * HH) * S_LEN + sp * 2;

    #pragma unroll 4
    for (int d = 0; d < HH; ++d) {
        float2 qv[4];
        #pragma unroll
        for (int j = 0; j < 4; ++j)
            qv[j] = *reinterpret_cast<const float2*>(qrow[j] + (size_t)d * S_LEN);
        const int dd = (d + ft) & 31;        // matches store rotation (f>>2 == ft)
        const int so = sp ^ (dd & 4);        // bank-spread XOR
        #pragma unroll
        for (int i = 0; i < 4; ++i) {
            const unsigned w = k_lds[((ft * 4 + i) * 32 + dd) * 8 + so];
            const float klo = __uint_as_float(w << 16);
            const float khi = __uint_as_float(w & 0xffff0000u);
            #pragma unroll
            for (int j = 0; j < 4; ++j) {
                acc[j][i][0] = fmaf(qv[j].x, klo, acc[j][i][0]);
                acc[j][i][1] = fmaf(qv[j].y, khi, acc[j][i][1]);
            }
        }
    }
    #pragma unroll
    for (int j = 0; j < 4; ++j)
        #pragma unroll
        for (int i = 0; i < 4; ++i) { acc[j][i][0] *= SCALE; acc[j][i][1] *= SCALE; }

    // ---------------- softmax over f (4 local f x 8 ft lanes) ----------------
    float mx[4][2];
    #pragma unroll
    for (int j = 0; j < 4; ++j) {
        #pragma unroll
        for (int e = 0; e < 2; ++e) {
            float m = fmaxf(fmaxf(acc[j][0][e], acc[j][1][e]),
                            fmaxf(acc[j][2][e], acc[j][3][e]));
            m = fmaxf(m, __shfl_xor(m, 8));
            m = fmaxf(m, __shfl_xor(m, 16));
            m = fmaxf(m, __shfl_xor(m, 32));
            mx[j][e] = m;
        }
    }
    // store logits, overwrite acc in place with exp(acc - m)
    #pragma unroll
    for (int j = 0; j < 4; ++j) {
        const int g = gt * 4 + j;
        #pragma unroll
        for (int i = 0; i < 4; ++i) {
            const int f = ft * 4 + i;
            const size_t o = (size_t)(baseB + g * GG + f) * S_LEN + s0 + sp * 2;
            *reinterpret_cast<float2*>(logit_out + o) = make_float2(acc[j][i][0], acc[j][i][1]);
            acc[j][i][0] = __expf(acc[j][i][0] - mx[j][0]);
            acc[j][i][1] = __expf(acc[j][i][1] - mx[j][1]);
        }
    }
    float inv[4][2];
    #pragma unroll
    for (int j = 0; j < 4; ++j) {
        #pragma unroll
        for (int e = 0; e < 2; ++e) {
            float s = acc[j][0][e] + acc[j][1][e] + acc[j][2][e] + acc[j][3][e];
            s += __shfl_xor(s, 8);
            s += __shfl_xor(s, 16);
            s += __shfl_xor(s, 32);
            inv[j][e] = __builtin_amdgcn_rcpf(s);
        }
    }
    // attn: global store + pack bf16 for the LDS buffer ([f][gt][sp^ft][j] layout,
    // j contiguous -> PV reads one conflict-free broadcast b128 per f)
    unsigned apack[4][4];   // [i][j], fully unrolled -> registers
    #pragma unroll
    for (int j = 0; j < 4; ++j) {
        const int g = gt * 4 + j;
        #pragma unroll
        for (int i = 0; i < 4; ++i) {
            const int f = ft * 4 + i;
            const float a0 = acc[j][i][0] * inv[j][0];
            const float a1 = acc[j][i][1] * inv[j][1];
            const size_t o = (size_t)(baseB + g * GG + f) * S_LEN + s0 + sp * 2;
            *reinterpret_cast<float2*>(attn_out + o) = make_float2(a0, a1);
            apack[i][j] = bf16pack(a0, a1);
        }
    }
    __syncthreads();   // all k_lds (QK) reads done; k_lds becomes the attn buffer
    #pragma unroll
    for (int i = 0; i < 4; ++i) {
        const int f = ft * 4 + i;
        uint4 w;
        w.x = apack[i][0]; w.y = apack[i][1]; w.z = apack[i][2]; w.w = apack[i][3];
        *reinterpret_cast<uint4*>(&k_lds[((f * 8 + gt) * 8 + (sp ^ ft)) * 4]) = w;
    }
    __syncthreads();

    // ---------------- PV: xacc[4g][4d][2s] ----------------
    float xacc[4][4][2];
    #pragma unroll
    for (int j = 0; j < 4; ++j)
        #pragma unroll
        for (int i = 0; i < 4; ++i) { xacc[j][i][0] = 0.f; xacc[j][i][1] = 0.f; }

    const int dt = ft;
    const int sov = sp ^ (dt & 4);   // v-row XOR: (f*32 + i*8 + dt) & 4 == dt & 4
    #pragma unroll 4
    for (int f = 0; f < GG; ++f) {
        const int fp = f >> 2;
        const uint4 wa = *reinterpret_cast<const uint4*>(
            &k_lds[((f * 8 + gt) * 8 + (sp ^ fp)) * 4]);
        float alo[4], ahi[4];
        alo[0] = __uint_as_float(wa.x << 16); ahi[0] = __uint_as_float(wa.x & 0xffff0000u);
        alo[1] = __uint_as_float(wa.y << 16); ahi[1] = __uint_as_float(wa.y & 0xffff0000u);
        alo[2] = __uint_as_float(wa.z << 16); ahi[2] = __uint_as_float(wa.z & 0xffff0000u);
        alo[3] = __uint_as_float(wa.w << 16); ahi[3] = __uint_as_float(wa.w & 0xffff0000u);
        #pragma unroll
        for (int i = 0; i < 4; ++i) {
            // d = dt*4+i stored at pi(d) = ((d&3)<<3)|(d>>2) = i*8 + dt
            const unsigned w = v_lds[(f * 32 + i * 8 + dt) * 8 + sov];
            const float vlo = __uint_as_float(w << 16);
            const float vhi = __uint_as_float(w & 0xffff0000u);
            #pragma unroll
            for (int j = 0; j < 4; ++j) {
                xacc[j][i][0] = fmaf(alo[j], vlo, xacc[j][i][0]);
                xacc[j][i][1] = fmaf(ahi[j], vhi, xacc[j][i][1]);
            }
        }
    }
    // store x: x[b, g*32+d, s]
    #pragma unroll
    for (int j = 0; j < 4; ++j) {
        const int g = gt * 4 + j;
        #pragma unroll
        for (int i = 0; i < 4; ++i) {
            const int d = dt * 4 + i;
            const size_t o = (size_t)(baseB + g * HH + d) * S_LEN + s0 + sp * 2;
            *reinterpret_cast<float2*>(x_out + o) = make_float2(xacc[j][i][0], xacc[j][i][1]);
        }
    }
}

extern "C" void kernel_launch(void* const* d_in, const int* in_sizes, int n_in,
                              void* d_out, int out_size, void* d_ws, size_t ws_size,
                              hipStream_t stream) {
    const float* q = (const float*)d_in[0];
    const float* k = (const float*)d_in[1];
    const float* v = (const float*)d_in[2];
    float* out = (float*)d_out;
    const int n = in_sizes[0];                  // B*G*H*S = 67108864
    const int B = n / (GG * HH * S_LEN);        // 16
    float* x_out     = out;
    float* attn_out  = out + (size_t)n;
    float* logit_out = out + (size_t)2 * n;
    const int nwg = B * (S_LEN / TS);           // 4096
    tamcad_fused<<<dim3(nwg), dim3(512), 0, stream>>>(q, k, v, x_out, attn_out, logit_out);
}